// Round 2
// baseline (1385.561 us; speedup 1.0000x reference)
//
#include <hip/hip_runtime.h>
#include <stdint.h>

// Triangle multiplication (outgoing), N=768, C=128.
// Pipeline:
//   K0: build interleaved bf16 weight matrix Wcat[768][128]:
//       rows 4c..4c+3 = wp[2c], wg[2c], wp[2c+1], wg[2c+1]  (c=0..127)
//       rows 512..639 = w_glin ; rows 640..767 = w_out
//   K1: per 64-point tile: LN stats via global loads + shuffle reduce (no xs
//       LDS tile -> 33KB LDS -> 4 blocks/CU); frag build re-reads pair from
//       L2 at fragment addresses; Phase D per-wave pipelined weight chunks
//       (counted vmcnt, no block barriers).
//   K2: 128 batched 768x768x768 bf16 GEMMs, double-buffered LDS 2-phase
//       pipeline (stage kb+1 issued before compute kb, 1 barrier/iter).
//   K3: vectorized transpose-stage o_t (bf16-pair LDS + XOR pair swizzle),
//       LN over c, w_out frags loaded per-lane from L2-hot Wcat (no wbuf ->
//       20KB LDS), epilogue per at-half to halve live acc regs.
// Workspace: 4*150994944 + 196608 = 604176384 bytes.

#define NN_F (768 * 768)

typedef float f32x4 __attribute__((ext_vector_type(4)));
typedef __bf16 bf16x8 __attribute__((ext_vector_type(8)));
typedef unsigned short u16x8 __attribute__((ext_vector_type(8)));

#define AS1 __attribute__((address_space(1)))
#define AS3 __attribute__((address_space(3)))

__device__ __forceinline__ unsigned short f2b(float f) {
  unsigned u = __builtin_bit_cast(unsigned, f);
  u = u + 0x7fffu + ((u >> 16) & 1u);
  return (unsigned short)(u >> 16);
}
__device__ __forceinline__ float b2f(unsigned short s) {
  return __builtin_bit_cast(float, ((unsigned)s) << 16);
}
__device__ __forceinline__ float sigf(float x) {
  return 1.0f / (1.0f + __expf(-x));
}

// ---------------------------------------------------------------- K0
__global__ __launch_bounds__(256) void k0_weights(
    const float* __restrict__ w_proj, const float* __restrict__ w_gate,
    const float* __restrict__ w_glin, const float* __restrict__ w_out,
    unsigned short* __restrict__ Wcat) {
  int idx = blockIdx.x * 256 + threadIdx.x;  // 768*128 total
  int r = idx >> 7, k = idx & 127;
  float v;
  if (r < 512) {
    int c = r >> 2, tt = r & 3;
    int row = 2 * c + (tt >> 1);
    v = (tt & 1) ? w_gate[row * 128 + k] : w_proj[row * 128 + k];
  } else if (r < 640) {
    v = w_glin[(r - 512) * 128 + k];
  } else {
    v = w_out[(r - 640) * 128 + k];
  }
  Wcat[idx] = f2b(v);
}

// ---------------------------------------------------------------- K1
__global__ __launch_bounds__(256, 4) void k1_proj(
    const float* __restrict__ pair, const float* __restrict__ lnw,
    const float* __restrict__ lnb, const unsigned short* __restrict__ Wcat,
    unsigned short* __restrict__ a_t, unsigned short* __restrict__ b_t,
    unsigned short* __restrict__ g) {
  __shared__ float muA[64], rsA[64];
  __shared__ unsigned short wbuf[32 * 512];  // wave-private weight slots, 32KB

  const int t = threadIdx.x;
  const int l = t & 63, w = t >> 6;
  const int lm = l & 15, lq = l >> 4;
  const size_t p0 = (size_t)blockIdx.x * 64;
  const float* src = pair + p0 * 128;

  // Prefetch weight steps 0 and 1 (chunk 0, both at-halves) into this
  // wave's slots; drained by the barrier below (data needed only later).
#pragma unroll
  for (int s0 = 0; s0 < 2; ++s0) {
    const int at = w * 2 + s0;
#pragma unroll
    for (int kt = 0; kt < 4; ++kt) {
      const unsigned short* gp =
          Wcat + (size_t)(at * 16 + lm) * 128 + kt * 32 + lq * 8;
      __builtin_amdgcn_global_load_lds((const AS1 void*)gp,
                                       (AS3 void*)(wbuf + (at * 4 + kt) * 512),
                                       16, 0, 0);
    }
  }

  // LN stats straight from global: lane owns row w*16+(l>>2), quarter l&3
  // (strided f32x4 -> 16 x 64B contiguous segments per wave instr), then
  // 2-step shuffle reduce within the 4-lane quarter group.
  {
    const int r = w * 16 + (l >> 2), q = l & 3;
    const float* rp = src + r * 128;
    float s1 = 0.f, s2 = 0.f;
#pragma unroll
    for (int e = 0; e < 8; ++e) {
      f32x4 v = *(const f32x4*)(rp + (q + e * 4) * 4);
#pragma unroll
      for (int j = 0; j < 4; ++j) {
        s1 += v[j];
        s2 += v[j] * v[j];
      }
    }
    s1 += __shfl_xor(s1, 1);
    s2 += __shfl_xor(s2, 1);
    s1 += __shfl_xor(s1, 2);
    s2 += __shfl_xor(s2, 2);
    if (q == 0) {
      float mu = s1 * (1.f / 128.f);
      float var = s2 * (1.f / 128.f) - mu * mu;
      muA[r] = mu;
      rsA[r] = rsqrtf(var + 1e-5f);
    }
  }
  __syncthreads();

  // Phase C: build B-operand frags (normalized, bf16) from a second global
  // read at exactly the fragment addresses (L2-hot: same 32KB tile as the
  // stats pass). Wave reads 16 fully-consumed 128B lines per (pt,kt).
  bf16x8 xfr[4][4];
#pragma unroll
  for (int kt = 0; kt < 4; ++kt) {
    const int ks = kt * 32 + lq * 8;
    f32x4 w0 = *(const f32x4*)&lnw[ks];
    f32x4 w1 = *(const f32x4*)&lnw[ks + 4];
    f32x4 c0 = *(const f32x4*)&lnb[ks];
    f32x4 c1 = *(const f32x4*)&lnb[ks + 4];
#pragma unroll
    for (int pt = 0; pt < 4; ++pt) {
      const int p = pt * 16 + lm;
      float rs = rsA[p], nmu = -muA[p] * rs;
      const float* xp = src + p * 128 + ks;
      f32x4 x0 = *(const f32x4*)xp;
      f32x4 x1 = *(const f32x4*)(xp + 4);
      union { bf16x8 v; __bf16 e[8]; } fr;
#pragma unroll
      for (int j = 0; j < 4; ++j) {
        fr.e[j] = (__bf16)((x0[j] * rs + nmu) * w0[j] + c0[j]);
        fr.e[4 + j] = (__bf16)((x1[j] * rs + nmu) * w1[j] + c1[j]);
      }
      xfr[pt][kt] = fr.v;
    }
  }
  __builtin_amdgcn_sched_barrier(0);  // pin all Phase-C VMEM above the loop
  // Phase D: 10 per-wave steps (5 chunks x 2 at-halves), no block barriers.
  // Slot parity = s&1; step s+2 reuses step s's slot. VMEM issue order per
  // step: [L(s+2) x4][stores(s) x8or4]; waits count ops younger than L(s):
  //   s=0,1: landed before barrier (no wait)
  //   s=2..8: st(s-2)=8 + L(s+1)=4 + st(s-1)=8 -> vmcnt(20)
  //   s=9:    st7=8 + st8=4                    -> vmcnt(12)
#pragma unroll
  for (int s = 0; s < 10; ++s) {
    if (s >= 2 && s <= 8)
      __builtin_amdgcn_s_waitcnt(0x4f74);  // vmcnt(20)
    else if (s == 9)
      __builtin_amdgcn_s_waitcnt(0x0f7c);  // vmcnt(12)
    const int at = w * 2 + (s & 1);
    bf16x8 af[4];
#pragma unroll
    for (int kt = 0; kt < 4; ++kt)
      af[kt] = *(const bf16x8*)&wbuf[(at * 4 + kt) * 512 + l * 8];
    __builtin_amdgcn_s_waitcnt(0xc07f);  // lgkmcnt(0): af regs live
    __builtin_amdgcn_sched_barrier(0);   // rule #18: no hoist past the wait
    if (s < 8) {  // prefetch step s+2 into the slot just consumed
      const int r0n = ((s + 2) >> 1) * 128;
#pragma unroll
      for (int kt = 0; kt < 4; ++kt) {
        const unsigned short* gp =
            Wcat + (size_t)(r0n + at * 16 + lm) * 128 + kt * 32 + lq * 8;
        __builtin_amdgcn_global_load_lds(
            (const AS1 void*)gp, (AS3 void*)(wbuf + (at * 4 + kt) * 512),
            16, 0, 0);
      }
    }
    f32x4 acc[4];
#pragma unroll
    for (int pt = 0; pt < 4; ++pt) acc[pt] = (f32x4){0.f, 0.f, 0.f, 0.f};
#pragma unroll
    for (int pt = 0; pt < 4; ++pt)
#pragma unroll
      for (int kt = 0; kt < 4; ++kt)
        acc[pt] = __builtin_amdgcn_mfma_f32_16x16x32_bf16(af[kt], xfr[pt][kt],
                                                          acc[pt], 0, 0, 0);
    // Epilogue: lane = point (col), regs = 4 consecutive weight rows
    const int wc = s >> 1;
    const int rbase = wc * 128 + at * 16 + lq * 4;
#pragma unroll
    for (int pt = 0; pt < 4; ++pt) {
      f32x4 d = acc[pt];
      size_t point = p0 + pt * 16 + lm;
      if (wc < 4) {
        int c = rbase >> 2;
        a_t[(size_t)c * NN_F + point] = f2b(d[0] * sigf(d[1]));
        b_t[(size_t)c * NN_F + point] = f2b(d[2] * sigf(d[3]));
      } else {
        int co = rbase - 512;
        union { unsigned long long ll; unsigned short u[4]; } pk;
        pk.u[0] = f2b(sigf(d[0]));
        pk.u[1] = f2b(sigf(d[1]));
        pk.u[2] = f2b(sigf(d[2]));
        pk.u[3] = f2b(sigf(d[3]));
        *(unsigned long long*)&g[point * 128 + co] = pk.ll;
      }
    }
  }
}

// ---------------------------------------------------------------- K2
__global__ __launch_bounds__(256) void k2_einsum(
    const unsigned short* __restrict__ a_t, const unsigned short* __restrict__ b_t,
    unsigned short* __restrict__ o_t) {
  __shared__ unsigned short As[2][128 * 32];
  __shared__ unsigned short Bs[2][128 * 32];
  const int t = threadIdx.x;
  const int l = t & 63, w = t >> 6;
  const int lm = l & 15, lq = l >> 4;
  const int c = blockIdx.z;
  const int m0 = blockIdx.y * 128, n0 = blockIdx.x * 128;
  const unsigned short* Ac = a_t + (size_t)c * NN_F;
  const unsigned short* Bc = b_t + (size_t)c * NN_F;
  const int wi = w >> 1, wj = w & 1;
  const int lrow = l >> 2, lk = (l & 3) * 8;
  f32x4 acc[4][4];
#pragma unroll
  for (int ti = 0; ti < 4; ++ti)
#pragma unroll
    for (int tj = 0; tj < 4; ++tj) acc[ti][tj] = (f32x4){0.f, 0.f, 0.f, 0.f};

  auto stage = [&](int buf, int kb) {
#pragma unroll
    for (int h = 0; h < 2; ++h) {
      int row = w * 32 + h * 16 + lrow;
      __builtin_amdgcn_global_load_lds(
          (const AS1 void*)(Ac + (size_t)(m0 + row) * 768 + kb * 32 + lk),
          (AS3 void*)(As[buf] + (w * 32 + h * 16) * 32), 16, 0, 0);
      __builtin_amdgcn_global_load_lds(
          (const AS1 void*)(Bc + (size_t)(n0 + row) * 768 + kb * 32 + lk),
          (AS3 void*)(Bs[buf] + (w * 32 + h * 16) * 32), 16, 0, 0);
    }
  };

  stage(0, 0);
  int cur = 0;
  for (int kb = 0; kb < 24; ++kb) {
    // Single barrier per K-step: its implicit vmcnt(0)+lgkmcnt(0) drain makes
    // buf[cur] ready (staged last iter, overlapped with last iter's MFMA) and
    // makes buf[cur^1] safe to overwrite (all waves' ds_reads drained).
    __syncthreads();
    if (kb < 23) stage(cur ^ 1, kb + 1);  // prefetch under this iter's MFMA
    bf16x8 af[4], bfr[4];
#pragma unroll
    for (int ti = 0; ti < 4; ++ti)
      af[ti] = *(const bf16x8*)&As[cur][(wi * 64 + ti * 16 + lm) * 32 + lq * 8];
#pragma unroll
    for (int tj = 0; tj < 4; ++tj)
      bfr[tj] = *(const bf16x8*)&Bs[cur][(wj * 64 + tj * 16 + lm) * 32 + lq * 8];
#pragma unroll
    for (int ti = 0; ti < 4; ++ti)
#pragma unroll
      for (int tj = 0; tj < 4; ++tj)
        acc[ti][tj] = __builtin_amdgcn_mfma_f32_16x16x32_bf16(
            af[ti], bfr[tj], acc[ti][tj], 0, 0, 0);
    cur ^= 1;
  }
  unsigned short* Oc = o_t + (size_t)c * NN_F;
#pragma unroll
  for (int ti = 0; ti < 4; ++ti) {
    int ib = m0 + wi * 64 + ti * 16 + lq * 4;
#pragma unroll
    for (int tj = 0; tj < 4; ++tj) {
      int j = n0 + wj * 64 + tj * 16 + lm;
      f32x4 d = acc[ti][tj];
#pragma unroll
      for (int r = 0; r < 4; ++r) Oc[(size_t)(ib + r) * 768 + j] = f2b(d[r]);
    }
  }
}

// ---------------------------------------------------------------- K3
__global__ __launch_bounds__(256, 4) void k3_out(
    const unsigned short* __restrict__ o_t, const float* __restrict__ lnw,
    const float* __restrict__ lnb, const unsigned short* __restrict__ Wcat,
    const unsigned short* __restrict__ g, float* __restrict__ out) {
  __shared__ unsigned short ys[64 * 136];  // bf16 pairs, XOR pair-swizzled
  __shared__ float red[8][64];
  __shared__ float muA[64], rsA[64];

  const int t = threadIdx.x;
  const int l = t & 63, w = t >> 6;
  const int lm = l & 15, lq = l >> 4;
  const size_t pblk = (size_t)blockIdx.x * 64;
  const int i = (int)(pblk / 768), j0 = (int)(pblk % 768);

  // Phase A: vectorized transposed stage o_t[c][i][j0..j0+63] -> ys[j][c].
  // Each thread: one j-octet (16B coalesced load = exactly one 128B line per
  // wave instr) for a channel PAIR (c, c+1); bf16 pair -> one b32 LDS write.
  // Pair slot swizzle sp = cp ^ (jg<<2) makes writes 2-way (free) and frag
  // reads uniform-bank.
  {
    const int jg = t & 7, cpb = t >> 3;  // j-octet 0..7, pair-base 0..31
#pragma unroll
    for (int cg = 0; cg < 2; ++cg) {
      int cp = cg * 32 + cpb;            // channel pair 0..63
      const unsigned short* srcp =
          o_t + (size_t)(cp * 2) * NN_F + (size_t)i * 768 + j0 + jg * 8;
      u16x8 v0 = *(const u16x8*)srcp;
      u16x8 v1 = *(const u16x8*)(srcp + NN_F);
      int sp = cp ^ (jg << 2);
#pragma unroll
      for (int m = 0; m < 8; ++m) {
        unsigned pk = (unsigned)v0[m] | ((unsigned)v1[m] << 16);
        *(unsigned*)&ys[(jg * 8 + m) * 136 + sp * 2] = pk;
      }
    }
  }
  __syncthreads();
  // LN stats over c (sum is order-free; swizzle is a within-row permutation)
  {
    int p = t & 63, q = t >> 6;
    const unsigned* rowp = (const unsigned*)&ys[p * 136];
    float s1 = 0.f, s2 = 0.f;
#pragma unroll
    for (int ii = 0; ii < 16; ++ii) {
      unsigned pk = rowp[q * 16 + ((ii + p) & 15)];
      float xa = b2f((unsigned short)(pk & 0xffffu));
      float xb = b2f((unsigned short)(pk >> 16));
      s1 += xa + xb;
      s2 += xa * xa + xb * xb;
    }
    red[q][p] = s1;
    red[q + 4][p] = s2;
  }
  __syncthreads();
  if (t < 64) {
    float s1 = red[0][t] + red[1][t] + red[2][t] + red[3][t];
    float s2 = red[4][t] + red[5][t] + red[6][t] + red[7][t];
    float mu = s1 * (1.f / 128.f);
    float var = s2 * (1.f / 128.f) - mu * mu;
    muA[t] = mu;
    rsA[t] = rsqrtf(var + 1e-5f);
  }
  __syncthreads();
  // frags of LN'd einsum output; unwind the pair swizzle:
  // pair block for channels ks..ks+7 sits at (kp ^ (jg_p<<2)), 4-aligned.
  bf16x8 yfr[4][4];
#pragma unroll
  for (int kt = 0; kt < 4; ++kt) {
    const int ks = kt * 32 + lq * 8;
    f32x4 w0 = *(const f32x4*)&lnw[ks];
    f32x4 w1 = *(const f32x4*)&lnw[ks + 4];
    f32x4 c0 = *(const f32x4*)&lnb[ks];
    f32x4 c1 = *(const f32x4*)&lnb[ks + 4];
    const int kp = ks >> 1;
#pragma unroll
    for (int pt = 0; pt < 4; ++pt) {
      const int p = pt * 16 + lm;
      float rs = rsA[p], nmu = -muA[p] * rs;
      int spos = (kp ^ ((p >> 3) << 2)) * 2;
      u16x8 raw = *(const u16x8*)&ys[p * 136 + spos];  // raw[n] = ch ks+n
      union { bf16x8 v; __bf16 e[8]; } fr;
#pragma unroll
      for (int j = 0; j < 4; ++j) {
        float x0 = b2f(raw[j]);
        float x1 = b2f(raw[4 + j]);
        fr.e[j] = (__bf16)((x0 * rs + nmu) * w0[j] + c0[j]);
        fr.e[4 + j] = (__bf16)((x1 * rs + nmu) * w1[j] + c1[j]);
      }
      yfr[pt][kt] = fr.v;
    }
  }
  // MFMA + epilogue per at-half. w_out frags come straight from Wcat rows
  // 640..767 via per-lane 16B global loads: 32KB shared by all 9216 blocks
  // -> L2-hot; removes wbuf (LDS 52->20KB) and the trailing vmcnt(0) drain.
  // Epilogue inside the at2 loop keeps only 4 acc regs live.
#pragma unroll
  for (int at2 = 0; at2 < 2; ++at2) {
    const int at = w * 2 + at2;
    bf16x8 af[4];
#pragma unroll
    for (int kt = 0; kt < 4; ++kt)
      af[kt] = *(const bf16x8*)(Wcat + (size_t)(640 + at * 16 + lm) * 128 +
                                kt * 32 + lq * 8);
    f32x4 acc[4];
#pragma unroll
    for (int pt = 0; pt < 4; ++pt) acc[pt] = (f32x4){0.f, 0.f, 0.f, 0.f};
#pragma unroll
    for (int pt = 0; pt < 4; ++pt)
#pragma unroll
      for (int kt = 0; kt < 4; ++kt)
        acc[pt] = __builtin_amdgcn_mfma_f32_16x16x32_bf16(af[kt], yfr[pt][kt],
                                                          acc[pt], 0, 0, 0);
    const int ob = at * 16 + lq * 4;
#pragma unroll
    for (int pt = 0; pt < 4; ++pt) {
      size_t point = pblk + pt * 16 + lm;
      f32x4 d = acc[pt];
      union { unsigned long long ll; unsigned short u[4]; } pk;
      pk.ll = *(const unsigned long long*)(g + point * 128 + ob);
      f32x4 r;
      r[0] = d[0] * b2f(pk.u[0]);
      r[1] = d[1] * b2f(pk.u[1]);
      r[2] = d[2] * b2f(pk.u[2]);
      r[3] = d[3] * b2f(pk.u[3]);
      *(f32x4*)&out[point * 128 + ob] = r;
    }
  }
}

// ---------------------------------------------------------------- launch
extern "C" void kernel_launch(void* const* d_in, const int* in_sizes, int n_in,
                              void* d_out, int out_size, void* d_ws, size_t ws_size,
                              hipStream_t stream) {
  const float* pair = (const float*)d_in[0];
  const float* ln_in_w = (const float*)d_in[1];
  const float* ln_in_b = (const float*)d_in[2];
  const float* w_proj = (const float*)d_in[3];
  const float* w_gate = (const float*)d_in[4];
  const float* ln_c_w = (const float*)d_in[5];
  const float* ln_c_b = (const float*)d_in[6];
  const float* w_out = (const float*)d_in[7];
  const float* w_glin = (const float*)d_in[8];
  float* out = (float*)d_out;

  char* ws = (char*)d_ws;
  const size_t SZ = (size_t)150994944;  // 128*768*768*2 bytes
  unsigned short* a_t = (unsigned short*)(ws);
  unsigned short* b_t = (unsigned short*)(ws + SZ);
  unsigned short* o_t = (unsigned short*)(ws + 2 * SZ);
  unsigned short* g = (unsigned short*)(ws + 3 * SZ);
  unsigned short* Wcat = (unsigned short*)(ws + 4 * SZ);

  hipLaunchKernelGGL(k0_weights, dim3(384), dim3(256), 0, stream,
                     w_proj, w_gate, w_glin, w_out, Wcat);
  hipLaunchKernelGGL(k1_proj, dim3(9216), dim3(256), 0, stream,
                     pair, ln_in_w, ln_in_b, Wcat, a_t, b_t, g);
  hipLaunchKernelGGL(k2_einsum, dim3(6, 6, 128), dim3(256), 0, stream,
                     a_t, b_t, o_t);
  hipLaunchKernelGGL(k3_out, dim3(9216), dim3(256), 0, stream,
                     o_t, ln_c_w, ln_c_b, Wcat, g, out);
}

// Round 3
// 1077.017 us; speedup vs baseline: 1.2865x; 1.2865x over previous
//
#include <hip/hip_runtime.h>
#include <stdint.h>

// Triangle multiplication (outgoing), N=768, C=128.
// Pipeline:
//   K0: build interleaved bf16 weight matrix Wcat[768][128]:
//       rows 4c..4c+3 = wp[2c], wg[2c], wp[2c+1], wg[2c+1]  (c=0..127)
//       rows 512..639 = w_glin ; rows 640..767 = w_out
//   K1: per 64-point tile: single coalesced pair read -> xs LDS tile; LN
//       stats from LDS; frags from LDS; Phase D weight frags loaded PER-LANE
//       from L2-hot Wcat (no wbuf) -> LDS 36.4KB -> 4 blocks/CU.
//   K2: 128 batched 768x768x768 bf16 GEMMs, double-buffered LDS 2-phase
//       pipeline; chunked XCD swizzle (each XCD owns 16 whole channels ->
//       A_c+B_c = 2.25MB resident in its 4MB L2).
//   K3: vectorized transpose-stage o_t (bf16-pair LDS + XOR pair swizzle),
//       LN over c, w_out frags per-lane from L2-hot Wcat, epilogue per
//       at-half.
// Workspace: 4*150994944 + 196608 = 604176384 bytes.

#define NN_F (768 * 768)

typedef float f32x4 __attribute__((ext_vector_type(4)));
typedef __bf16 bf16x8 __attribute__((ext_vector_type(8)));
typedef unsigned short u16x8 __attribute__((ext_vector_type(8)));

#define AS1 __attribute__((address_space(1)))
#define AS3 __attribute__((address_space(3)))

__device__ __forceinline__ unsigned short f2b(float f) {
  unsigned u = __builtin_bit_cast(unsigned, f);
  u = u + 0x7fffu + ((u >> 16) & 1u);
  return (unsigned short)(u >> 16);
}
__device__ __forceinline__ float b2f(unsigned short s) {
  return __builtin_bit_cast(float, ((unsigned)s) << 16);
}
__device__ __forceinline__ float sigf(float x) {
  return 1.0f / (1.0f + __expf(-x));
}

// ---------------------------------------------------------------- K0
__global__ __launch_bounds__(256) void k0_weights(
    const float* __restrict__ w_proj, const float* __restrict__ w_gate,
    const float* __restrict__ w_glin, const float* __restrict__ w_out,
    unsigned short* __restrict__ Wcat) {
  int idx = blockIdx.x * 256 + threadIdx.x;  // 768*128 total
  int r = idx >> 7, k = idx & 127;
  float v;
  if (r < 512) {
    int c = r >> 2, tt = r & 3;
    int row = 2 * c + (tt >> 1);
    v = (tt & 1) ? w_gate[row * 128 + k] : w_proj[row * 128 + k];
  } else if (r < 640) {
    v = w_glin[(r - 512) * 128 + k];
  } else {
    v = w_out[(r - 640) * 128 + k];
  }
  Wcat[idx] = f2b(v);
}

// ---------------------------------------------------------------- K1
__global__ __launch_bounds__(256, 4) void k1_proj(
    const float* __restrict__ pair, const float* __restrict__ lnw,
    const float* __restrict__ lnb, const unsigned short* __restrict__ Wcat,
    unsigned short* __restrict__ a_t, unsigned short* __restrict__ b_t,
    unsigned short* __restrict__ g) {
  __shared__ float xs[64 * 132];  // raw pair tile, padded rows (33.8KB)
  __shared__ float red[8][64];
  __shared__ float muA[64], rsA[64];

  const int t = threadIdx.x;
  const int l = t & 63, w = t >> 6;
  const int lm = l & 15, lq = l >> 4;
  const size_t p0 = (size_t)blockIdx.x * 64;

  // Phase A: single coalesced read of 64 points x 128 channels (compulsory
  // HBM traffic, exactly once).
  const float* src = pair + p0 * 128;
#pragma unroll
  for (int v = 0; v < 8; ++v) {
    int fi = (v * 256 + t) * 4;
    int p = fi >> 7, c = fi & 127;
    f32x4 d = *(const f32x4*)(src + fi);
    *(f32x4*)&xs[p * 132 + c] = d;
  }
  __syncthreads();
  // Phase B: LN stats (rotated read order keeps bank conflicts ~2-way)
  {
    int p = t & 63, q = t >> 6;
    float s1 = 0.f, s2 = 0.f;
#pragma unroll
    for (int cc = 0; cc < 32; ++cc) {
      float x = xs[p * 132 + q * 32 + ((cc + p) & 31)];
      s1 += x;
      s2 += x * x;
    }
    red[q][p] = s1;
    red[q + 4][p] = s2;
  }
  __syncthreads();
  if (t < 64) {
    float s1 = red[0][t] + red[1][t] + red[2][t] + red[3][t];
    float s2 = red[4][t] + red[5][t] + red[6][t] + red[7][t];
    float mu = s1 * (1.f / 128.f);
    float var = s2 * (1.f / 128.f) - mu * mu;
    muA[t] = mu;
    rsA[t] = rsqrtf(var + 1e-5f);
  }
  __syncthreads();
  // Phase C: build B-operand frags (normalized, bf16). Vector LDS reads
  // (row stride 132 f32 = 33 x 16B superbanks -> 2-way on b128, free).
  bf16x8 xfr[4][4];
#pragma unroll
  for (int kt = 0; kt < 4; ++kt) {
    const int ks = kt * 32 + lq * 8;
    f32x4 w0 = *(const f32x4*)&lnw[ks];
    f32x4 w1 = *(const f32x4*)&lnw[ks + 4];
    f32x4 c0 = *(const f32x4*)&lnb[ks];
    f32x4 c1 = *(const f32x4*)&lnb[ks + 4];
#pragma unroll
    for (int pt = 0; pt < 4; ++pt) {
      const int p = pt * 16 + lm;
      float rs = rsA[p], nmu = -muA[p] * rs;
      f32x4 x0 = *(const f32x4*)&xs[p * 132 + ks];
      f32x4 x1 = *(const f32x4*)&xs[p * 132 + ks + 4];
      union { bf16x8 v; __bf16 e[8]; } fr;
#pragma unroll
      for (int j = 0; j < 4; ++j) {
        fr.e[j] = (__bf16)((x0[j] * rs + nmu) * w0[j] + c0[j]);
        fr.e[4 + j] = (__bf16)((x1[j] * rs + nmu) * w1[j] + c1[j]);
      }
      xfr[pt][kt] = fr.v;
    }
  }
  // Phase D: 10 steps (5 chunks x 2 at-halves). Weight frags per-lane from
  // Wcat (192KB, shared by all 9216 blocks -> L2-hot). No wbuf, no barriers,
  // no vmcnt bookkeeping; 16 waves/CU hide the L2 latency.
#pragma unroll
  for (int s = 0; s < 10; ++s) {
    const int at = w * 2 + (s & 1);
    const int wc = s >> 1;
    const int r0 = wc * 128;
    bf16x8 af[4];
#pragma unroll
    for (int kt = 0; kt < 4; ++kt)
      af[kt] = *(const bf16x8*)(Wcat + (size_t)(r0 + at * 16 + lm) * 128 +
                                kt * 32 + lq * 8);
    f32x4 acc[4];
#pragma unroll
    for (int pt = 0; pt < 4; ++pt) acc[pt] = (f32x4){0.f, 0.f, 0.f, 0.f};
#pragma unroll
    for (int pt = 0; pt < 4; ++pt)
#pragma unroll
      for (int kt = 0; kt < 4; ++kt)
        acc[pt] = __builtin_amdgcn_mfma_f32_16x16x32_bf16(af[kt], xfr[pt][kt],
                                                          acc[pt], 0, 0, 0);
    // Epilogue: lane = point (col), regs = 4 consecutive weight rows
    const int rbase = r0 + at * 16 + lq * 4;
#pragma unroll
    for (int pt = 0; pt < 4; ++pt) {
      f32x4 d = acc[pt];
      size_t point = p0 + pt * 16 + lm;
      if (wc < 4) {
        int c = rbase >> 2;
        a_t[(size_t)c * NN_F + point] = f2b(d[0] * sigf(d[1]));
        b_t[(size_t)c * NN_F + point] = f2b(d[2] * sigf(d[3]));
      } else {
        int co = rbase - 512;
        union { unsigned long long ll; unsigned short u[4]; } pk;
        pk.u[0] = f2b(sigf(d[0]));
        pk.u[1] = f2b(sigf(d[1]));
        pk.u[2] = f2b(sigf(d[2]));
        pk.u[3] = f2b(sigf(d[3]));
        *(unsigned long long*)&g[point * 128 + co] = pk.ll;
      }
    }
  }
}

// ---------------------------------------------------------------- K2
__global__ __launch_bounds__(256) void k2_einsum(
    const unsigned short* __restrict__ a_t, const unsigned short* __restrict__ b_t,
    unsigned short* __restrict__ o_t) {
  __shared__ unsigned short As[2][128 * 32];
  __shared__ unsigned short Bs[2][128 * 32];
  const int t = threadIdx.x;
  const int l = t & 63, w = t >> 6;
  const int lm = l & 15, lq = l >> 4;
  // Chunked XCD swizzle (grid 4608 = 8 XCDs x 576; round-robin dispatch ->
  // bid%8 = XCD). Each XCD owns 16 whole channels: A_c+B_c = 2.25MB resident
  // in its private 4MB L2; within a channel, 6 n-blocks share each A-panel.
  const int bid = blockIdx.x;
  const int nb = (bid & 7) * 576 + (bid >> 3);
  const int c = nb / 36;
  const int rem = nb % 36;
  const int m0 = (rem / 6) * 128, n0 = (rem % 6) * 128;
  const unsigned short* Ac = a_t + (size_t)c * NN_F;
  const unsigned short* Bc = b_t + (size_t)c * NN_F;
  const int wi = w >> 1, wj = w & 1;
  const int lrow = l >> 2, lk = (l & 3) * 8;
  f32x4 acc[4][4];
#pragma unroll
  for (int ti = 0; ti < 4; ++ti)
#pragma unroll
    for (int tj = 0; tj < 4; ++tj) acc[ti][tj] = (f32x4){0.f, 0.f, 0.f, 0.f};

  auto stage = [&](int buf, int kb) {
#pragma unroll
    for (int h = 0; h < 2; ++h) {
      int row = w * 32 + h * 16 + lrow;
      __builtin_amdgcn_global_load_lds(
          (const AS1 void*)(Ac + (size_t)(m0 + row) * 768 + kb * 32 + lk),
          (AS3 void*)(As[buf] + (w * 32 + h * 16) * 32), 16, 0, 0);
      __builtin_amdgcn_global_load_lds(
          (const AS1 void*)(Bc + (size_t)(n0 + row) * 768 + kb * 32 + lk),
          (AS3 void*)(Bs[buf] + (w * 32 + h * 16) * 32), 16, 0, 0);
    }
  };

  stage(0, 0);
  int cur = 0;
  for (int kb = 0; kb < 24; ++kb) {
    // Single barrier per K-step: its implicit vmcnt(0)+lgkmcnt(0) drain makes
    // buf[cur] ready (staged last iter, overlapped with last iter's MFMA) and
    // makes buf[cur^1] safe to overwrite (all waves' ds_reads drained).
    __syncthreads();
    if (kb < 23) stage(cur ^ 1, kb + 1);  // prefetch under this iter's MFMA
    bf16x8 af[4], bfr[4];
#pragma unroll
    for (int ti = 0; ti < 4; ++ti)
      af[ti] = *(const bf16x8*)&As[cur][(wi * 64 + ti * 16 + lm) * 32 + lq * 8];
#pragma unroll
    for (int tj = 0; tj < 4; ++tj)
      bfr[tj] = *(const bf16x8*)&Bs[cur][(wj * 64 + tj * 16 + lm) * 32 + lq * 8];
#pragma unroll
    for (int ti = 0; ti < 4; ++ti)
#pragma unroll
      for (int tj = 0; tj < 4; ++tj)
        acc[ti][tj] = __builtin_amdgcn_mfma_f32_16x16x32_bf16(
            af[ti], bfr[tj], acc[ti][tj], 0, 0, 0);
    cur ^= 1;
  }
  unsigned short* Oc = o_t + (size_t)c * NN_F;
#pragma unroll
  for (int ti = 0; ti < 4; ++ti) {
    int ib = m0 + wi * 64 + ti * 16 + lq * 4;
#pragma unroll
    for (int tj = 0; tj < 4; ++tj) {
      int j = n0 + wj * 64 + tj * 16 + lm;
      f32x4 d = acc[ti][tj];
#pragma unroll
      for (int r = 0; r < 4; ++r) Oc[(size_t)(ib + r) * 768 + j] = f2b(d[r]);
    }
  }
}

// ---------------------------------------------------------------- K3
__global__ __launch_bounds__(256, 4) void k3_out(
    const unsigned short* __restrict__ o_t, const float* __restrict__ lnw,
    const float* __restrict__ lnb, const unsigned short* __restrict__ Wcat,
    const unsigned short* __restrict__ g, float* __restrict__ out) {
  __shared__ unsigned short ys[64 * 136];  // bf16 pairs, XOR pair-swizzled
  __shared__ float red[8][64];
  __shared__ float muA[64], rsA[64];

  const int t = threadIdx.x;
  const int l = t & 63, w = t >> 6;
  const int lm = l & 15, lq = l >> 4;
  const size_t pblk = (size_t)blockIdx.x * 64;
  const int i = (int)(pblk / 768), j0 = (int)(pblk % 768);

  // Phase A: vectorized transposed stage o_t[c][i][j0..j0+63] -> ys[j][c].
  // Each thread: one j-octet (16B coalesced load) for a channel PAIR; bf16
  // pair -> one b32 LDS write. Pair slot swizzle sp = cp ^ (jg<<2) makes
  // writes 2-way (free) and frag reads uniform-bank.
  {
    const int jg = t & 7, cpb = t >> 3;  // j-octet 0..7, pair-base 0..31
#pragma unroll
    for (int cg = 0; cg < 2; ++cg) {
      int cp = cg * 32 + cpb;            // channel pair 0..63
      const unsigned short* srcp =
          o_t + (size_t)(cp * 2) * NN_F + (size_t)i * 768 + j0 + jg * 8;
      u16x8 v0 = *(const u16x8*)srcp;
      u16x8 v1 = *(const u16x8*)(srcp + NN_F);
      int sp = cp ^ (jg << 2);
#pragma unroll
      for (int m = 0; m < 8; ++m) {
        unsigned pk = (unsigned)v0[m] | ((unsigned)v1[m] << 16);
        *(unsigned*)&ys[(jg * 8 + m) * 136 + sp * 2] = pk;
      }
    }
  }
  __syncthreads();
  // LN stats over c (sum is order-free; swizzle is a within-row permutation)
  {
    int p = t & 63, q = t >> 6;
    const unsigned* rowp = (const unsigned*)&ys[p * 136];
    float s1 = 0.f, s2 = 0.f;
#pragma unroll
    for (int ii = 0; ii < 16; ++ii) {
      unsigned pk = rowp[q * 16 + ((ii + p) & 15)];
      float xa = b2f((unsigned short)(pk & 0xffffu));
      float xb = b2f((unsigned short)(pk >> 16));
      s1 += xa + xb;
      s2 += xa * xa + xb * xb;
    }
    red[q][p] = s1;
    red[q + 4][p] = s2;
  }
  __syncthreads();
  if (t < 64) {
    float s1 = red[0][t] + red[1][t] + red[2][t] + red[3][t];
    float s2 = red[4][t] + red[5][t] + red[6][t] + red[7][t];
    float mu = s1 * (1.f / 128.f);
    float var = s2 * (1.f / 128.f) - mu * mu;
    muA[t] = mu;
    rsA[t] = rsqrtf(var + 1e-5f);
  }
  __syncthreads();
  // frags of LN'd einsum output; unwind the pair swizzle:
  // pair block for channels ks..ks+7 sits at (kp ^ (jg_p<<2)), 4-aligned.
  bf16x8 yfr[4][4];
#pragma unroll
  for (int kt = 0; kt < 4; ++kt) {
    const int ks = kt * 32 + lq * 8;
    f32x4 w0 = *(const f32x4*)&lnw[ks];
    f32x4 w1 = *(const f32x4*)&lnw[ks + 4];
    f32x4 c0 = *(const f32x4*)&lnb[ks];
    f32x4 c1 = *(const f32x4*)&lnb[ks + 4];
    const int kp = ks >> 1;
#pragma unroll
    for (int pt = 0; pt < 4; ++pt) {
      const int p = pt * 16 + lm;
      float rs = rsA[p], nmu = -muA[p] * rs;
      int spos = (kp ^ ((p >> 3) << 2)) * 2;
      u16x8 raw = *(const u16x8*)&ys[p * 136 + spos];  // raw[n] = ch ks+n
      union { bf16x8 v; __bf16 e[8]; } fr;
#pragma unroll
      for (int j = 0; j < 4; ++j) {
        float x0 = b2f(raw[j]);
        float x1 = b2f(raw[4 + j]);
        fr.e[j] = (__bf16)((x0 * rs + nmu) * w0[j] + c0[j]);
        fr.e[4 + j] = (__bf16)((x1 * rs + nmu) * w1[j] + c1[j]);
      }
      yfr[pt][kt] = fr.v;
    }
  }
  // MFMA + epilogue per at-half. w_out frags per-lane from L2-hot Wcat rows
  // 640..767. Epilogue inside the at2 loop keeps only 4 acc regs live.
#pragma unroll
  for (int at2 = 0; at2 < 2; ++at2) {
    const int at = w * 2 + at2;
    bf16x8 af[4];
#pragma unroll
    for (int kt = 0; kt < 4; ++kt)
      af[kt] = *(const bf16x8*)(Wcat + (size_t)(640 + at * 16 + lm) * 128 +
                                kt * 32 + lq * 8);
    f32x4 acc[4];
#pragma unroll
    for (int pt = 0; pt < 4; ++pt) acc[pt] = (f32x4){0.f, 0.f, 0.f, 0.f};
#pragma unroll
    for (int pt = 0; pt < 4; ++pt)
#pragma unroll
      for (int kt = 0; kt < 4; ++kt)
        acc[pt] = __builtin_amdgcn_mfma_f32_16x16x32_bf16(af[kt], yfr[pt][kt],
                                                          acc[pt], 0, 0, 0);
    const int ob = at * 16 + lq * 4;
#pragma unroll
    for (int pt = 0; pt < 4; ++pt) {
      size_t point = pblk + pt * 16 + lm;
      f32x4 d = acc[pt];
      union { unsigned long long ll; unsigned short u[4]; } pk;
      pk.ll = *(const unsigned long long*)(g + point * 128 + ob);
      f32x4 r;
      r[0] = d[0] * b2f(pk.u[0]);
      r[1] = d[1] * b2f(pk.u[1]);
      r[2] = d[2] * b2f(pk.u[2]);
      r[3] = d[3] * b2f(pk.u[3]);
      *(f32x4*)&out[point * 128 + ob] = r;
    }
  }
}

// ---------------------------------------------------------------- launch
extern "C" void kernel_launch(void* const* d_in, const int* in_sizes, int n_in,
                              void* d_out, int out_size, void* d_ws, size_t ws_size,
                              hipStream_t stream) {
  const float* pair = (const float*)d_in[0];
  const float* ln_in_w = (const float*)d_in[1];
  const float* ln_in_b = (const float*)d_in[2];
  const float* w_proj = (const float*)d_in[3];
  const float* w_gate = (const float*)d_in[4];
  const float* ln_c_w = (const float*)d_in[5];
  const float* ln_c_b = (const float*)d_in[6];
  const float* w_out = (const float*)d_in[7];
  const float* w_glin = (const float*)d_in[8];
  float* out = (float*)d_out;

  char* ws = (char*)d_ws;
  const size_t SZ = (size_t)150994944;  // 128*768*768*2 bytes
  unsigned short* a_t = (unsigned short*)(ws);
  unsigned short* b_t = (unsigned short*)(ws + SZ);
  unsigned short* o_t = (unsigned short*)(ws + 2 * SZ);
  unsigned short* g = (unsigned short*)(ws + 3 * SZ);
  unsigned short* Wcat = (unsigned short*)(ws + 4 * SZ);

  hipLaunchKernelGGL(k0_weights, dim3(384), dim3(256), 0, stream,
                     w_proj, w_gate, w_glin, w_out, Wcat);
  hipLaunchKernelGGL(k1_proj, dim3(9216), dim3(256), 0, stream,
                     pair, ln_in_w, ln_in_b, Wcat, a_t, b_t, g);
  hipLaunchKernelGGL(k2_einsum, dim3(4608), dim3(256), 0, stream,
                     a_t, b_t, o_t);
  hipLaunchKernelGGL(k3_out, dim3(9216), dim3(256), 0, stream,
                     o_t, ln_c_w, ln_c_b, Wcat, g, out);
}